// Round 5
// baseline (3060.978 us; speedup 1.0000x reference)
//
#include <hip/hip_runtime.h>
#include <hip/hip_bf16.h>

#define BB 256
#define TT 512
#define XS 40
#define HS 128
#define GS 512  // 4*HS

enum { MODE_PROJ = 0, MODE_FLAT = 1, MODE_CONCAT = 2 };

__device__ __forceinline__ float fast_sigmoid(float x) {
    return __frcp_rn(1.0f + __expf(-x));
}
__device__ __forceinline__ float fast_tanh(float x) {
    x = fminf(fmaxf(x, -15.0f), 15.0f);
    float e = __expf(2.0f * x);
    return (e - 1.0f) * __frcp_rn(e + 1.0f);
}

// ---------------- gemm3: A staged once, N-chunks looped in-block ----------------
template <int K, int NS, int MODE, bool RELU>
__global__ __launch_bounds__(512) void gemm3(
    const float* __restrict__ A, const float* __restrict__ A2,
    const float* __restrict__ W, const float* __restrict__ b1p,
    const float* __restrict__ b2p, float* __restrict__ out,
    int Tc, int t0, int ooff) {
    __shared__ float at[K][132];
    __shared__ float wt[K][68];
    const int tid = threadIdx.x;
    const int row0 = blockIdx.x * 128;
    const int tx = tid & 15;
    const int ty = tid >> 4;

    for (int idx = tid; idx < 128 * K; idx += 512) {
        int m = idx / K, k = idx - m * K;
        int mg = row0 + m;
        float v;
        if (MODE == MODE_PROJ) {
            int b = mg / Tc, tt = mg - b * Tc;
            v = A[(size_t)(b * TT + t0 + tt) * K + k];
        } else if (MODE == MODE_FLAT) {
            v = A[(size_t)(mg + t0) * K + k];
        } else {
            int mgg = mg + t0;
            v = (k < XS) ? A[(size_t)mgg * XS + k] : A2[(size_t)mgg * HS + (k - XS)];
        }
        at[k][m] = v;
    }
    __syncthreads();

    for (int nc = 0; nc < NS / 64; ++nc) {
        for (int idx = tid; idx < 64 * K; idx += 512) {
            int n = idx / K, k = idx - n * K;
            wt[k][n] = W[(size_t)(nc * 64 + n) * K + k];
        }
        __syncthreads();

        float acc[4][4] = {};
#pragma unroll 4
        for (int k = 0; k < K; ++k) {
            float4 av = *(const float4*)&at[k][ty * 4];
            float4 wv = *(const float4*)&wt[k][tx * 4];
            float aa[4] = {av.x, av.y, av.z, av.w};
            float ww[4] = {wv.x, wv.y, wv.z, wv.w};
#pragma unroll
            for (int i = 0; i < 4; i++)
#pragma unroll
                for (int j = 0; j < 4; j++) acc[i][j] = fmaf(aa[i], ww[j], acc[i][j]);
        }

        int nb = nc * 64 + tx * 4;
        float4 bv = *(const float4*)&b1p[nb];
        if (MODE == MODE_PROJ) {
            float4 b2v = *(const float4*)&b2p[nb];
            bv.x += b2v.x; bv.y += b2v.y; bv.z += b2v.z; bv.w += b2v.w;
        }
#pragma unroll
        for (int i = 0; i < 4; i++) {
            int m = row0 + ty * 4 + i;
            size_t obase = (MODE == MODE_PROJ) ? (size_t)m * NS : (size_t)(m + ooff) * NS;
            float4 o;
            o.x = acc[i][0] + bv.x; o.y = acc[i][1] + bv.y;
            o.z = acc[i][2] + bv.z; o.w = acc[i][3] + bv.w;
            if (RELU) {
                o.x = fmaxf(o.x, 0.f); o.y = fmaxf(o.y, 0.f);
                o.z = fmaxf(o.z, 0.f); o.w = fmaxf(o.w, 0.f);
            }
            *(float4*)&out[obase + nb] = o;
        }
        __syncthreads();
    }
}

// ---------------- recurrence: waves_per_eu(4,4) + one-shot pin ----------------
// amdgpu_waves_per_eu(4,4): allocator knows occupancy is capped at 4 waves/EU,
// so the 128-VGPR budget is free -> no reason to demote the 64 weight regs.
// One-shot asm pin: weight values become volatile-asm outputs (no memory
// provenance) -> rematerializing via reload is illegal inside the loop.
#define WLOAD(i) float4 w##i = wr[i];
#define PIN4(i) asm volatile("" : "+v"(w##i.x), "+v"(w##i.y), "+v"(w##i.z), "+v"(w##i.w));
#define DOT(i)                                    \
    {                                             \
        float4 hv = h4[i];                        \
        s0 = fmaf(w##i.x, hv.x, s0);              \
        s1 = fmaf(w##i.y, hv.y, s1);              \
        s2 = fmaf(w##i.z, hv.z, s2);              \
        s3 = fmaf(w##i.w, hv.w, s3);              \
    }

__global__ __attribute__((amdgpu_flat_work_group_size(1024, 1024), amdgpu_waves_per_eu(4, 4)))
void lstm_rec5(
    const float* __restrict__ Whh, const float* __restrict__ xW,
    const float* __restrict__ h0, const float* __restrict__ c0,
    float* __restrict__ hstate, float* __restrict__ cstate,
    float* __restrict__ y, int Tc, int t0) {
    const int b = blockIdx.x;
    const int tid = threadIdx.x;
    const int gate = tid >> 1;   // 0..511
    const int half = tid & 1;    // which 64-chunk of the dot
    __shared__ __align__(16) float h_sh[HS];
    __shared__ float act[GS];

    const float4* wr = (const float4*)(Whh + (size_t)gate * HS + half * 64);
    WLOAD(0) WLOAD(1) WLOAD(2) WLOAD(3) WLOAD(4) WLOAD(5) WLOAD(6) WLOAD(7)
    WLOAD(8) WLOAD(9) WLOAD(10) WLOAD(11) WLOAD(12) WLOAD(13) WLOAD(14) WLOAD(15)
    // one-shot pin (outside the loop)
    PIN4(0) PIN4(1) PIN4(2) PIN4(3) PIN4(4) PIN4(5) PIN4(6) PIN4(7)
    PIN4(8) PIN4(9) PIN4(10) PIN4(11) PIN4(12) PIN4(13) PIN4(14) PIN4(15)

    float c = 0.0f;
    if (tid < HS) {
        float hv;
        if (t0 == 0) {
            hv = h0[(size_t)b * HS + tid];
            c = c0[(size_t)b * HS + tid];
        } else {
            hv = hstate[(size_t)b * HS + tid];
            c = cstate[(size_t)b * HS + tid];
        }
        h_sh[tid] = hv;
    }
    __syncthreads();

    const float* xWrow = xW + (size_t)b * Tc * GS;
    float* yrow = y + ((size_t)b * TT + t0) * HS;
    const float4* h4 = (const float4*)h_sh + half * 16;
    const int gtype = gate >> 7;  // 0=i 1=f 2=g 3=o (wave-uniform)

    float a_cur = (half == 0) ? xWrow[gate] : 0.0f;  // t = 0 prefetch

    for (int t = 0; t < Tc; ++t) {
        int tn = (t + 1 < Tc) ? t + 1 : t;
        float a_nxt = (half == 0) ? xWrow[(size_t)tn * GS + gate] : 0.0f;

        float s0 = 0.f, s1 = 0.f, s2 = 0.f, s3 = 0.f;
        DOT(0) DOT(1) DOT(2) DOT(3) DOT(4) DOT(5) DOT(6) DOT(7)
        DOT(8) DOT(9) DOT(10) DOT(11) DOT(12) DOT(13) DOT(14) DOT(15)
        float v = (s0 + s1) + (s2 + s3);
        v += __shfl_xor(v, 1);  // partner lane holds other half of the dot
        if (half == 0) {
            v += a_cur;
            act[gate] = (gtype == 2) ? fast_tanh(v) : fast_sigmoid(v);
        }
        __syncthreads();
        if (tid < HS) {
            float iv = act[tid], fv = act[HS + tid], gg = act[2 * HS + tid], ov = act[3 * HS + tid];
            c = fmaf(fv, c, iv * gg);
            float hv = ov * fast_tanh(c);
            h_sh[tid] = hv;
            yrow[(size_t)t * HS + tid] = hv;
        }
        __syncthreads();
        a_cur = a_nxt;
    }
    if (tid < HS) {
        hstate[(size_t)b * HS + tid] = h_sh[tid];
        cstate[(size_t)b * HS + tid] = c;
    }
}

// out[row] = dot(z2[row,:], W3[0,:]) + b3 — one wave per row
__global__ __launch_bounds__(256) void head_dot(
    const float* __restrict__ z2, const float* __restrict__ W3,
    const float* __restrict__ b3, float* __restrict__ out) {
    const int wave = threadIdx.x >> 6, lane = threadIdx.x & 63;
    const int row = blockIdx.x * 4 + wave;
    const float* zr = z2 + (size_t)row * HS;
    float v = zr[lane] * W3[lane] + zr[64 + lane] * W3[64 + lane];
#pragma unroll
    for (int m = 32; m >= 1; m >>= 1) v += __shfl_xor(v, m, 64);
    if (lane == 0) out[row] = v + b3[0];
}

extern "C" void kernel_launch(void* const* d_in, const int* in_sizes, int n_in,
                              void* d_out, int out_size, void* d_ws, size_t ws_size,
                              hipStream_t stream) {
    const float* x = (const float*)d_in[0];
    const float* h0 = (const float*)d_in[1];
    const float* c0 = (const float*)d_in[2];
    const float* Wih[3] = {(const float*)d_in[3], (const float*)d_in[7], (const float*)d_in[11]};
    const float* Whh[3] = {(const float*)d_in[4], (const float*)d_in[8], (const float*)d_in[12]};
    const float* bih[3] = {(const float*)d_in[5], (const float*)d_in[9], (const float*)d_in[13]};
    const float* bhh[3] = {(const float*)d_in[6], (const float*)d_in[10], (const float*)d_in[14]};
    const float* W1 = (const float*)d_in[15];
    const float* b1 = (const float*)d_in[16];
    const float* W2 = (const float*)d_in[17];
    const float* b2 = (const float*)d_in[18];
    const float* W3 = (const float*)d_in[19];
    const float* b3 = (const float*)d_in[20];
    float* outp = (float*)d_out;

    // workspace layout: y[B,T,H] | xW[B,Tc,4H] | hstate[B,H] | cstate[B,H]
    int Tc = TT;
    while (Tc > 8) {
        size_t need = ((size_t)BB * TT * HS + (size_t)BB * Tc * GS + 2 * (size_t)BB * HS) * 4;
        if (need <= ws_size) break;
        Tc >>= 1;
    }
    float* yb = (float*)d_ws;
    float* xw = yb + (size_t)BB * TT * HS;
    float* hs = xw + (size_t)BB * Tc * GS;
    float* cs = hs + (size_t)BB * HS;

    for (int l = 0; l < 3; ++l) {
        for (int t0 = 0; t0 < TT; t0 += Tc) {
            dim3 gp(BB * Tc / 128);
            if (l == 0)
                gemm3<XS, GS, MODE_PROJ, false><<<gp, 512, 0, stream>>>(
                    x, nullptr, Wih[0], bih[0], bhh[0], xw, Tc, t0, 0);
            else
                gemm3<HS, GS, MODE_PROJ, false><<<gp, 512, 0, stream>>>(
                    yb, nullptr, Wih[l], bih[l], bhh[l], xw, Tc, t0, 0);
            lstm_rec5<<<BB, 1024, 0, stream>>>(Whh[l], xw,
                                               h0 + (size_t)l * BB * HS, c0 + (size_t)l * BB * HS,
                                               hs, cs, yb, Tc, t0);
        }
    }

    // MLP head, row-chunked: z1 (local rows) lives in xw buffer
    const int totalRows = BB * TT;
    int Rc = BB * Tc * (GS / HS);
    if (Rc > totalRows) Rc = totalRows;
    for (int r0 = 0; r0 < totalRows; r0 += Rc) {
        dim3 gm(Rc / 128);
        gemm3<XS + HS, HS, MODE_CONCAT, true><<<gm, 512, 0, stream>>>(
            x, yb, W1, b1, nullptr, xw, 0, r0, 0);
        gemm3<HS, HS, MODE_FLAT, true><<<gm, 512, 0, stream>>>(
            xw, nullptr, W2, b2, nullptr, yb, 0, 0, r0);
    }
    head_dot<<<totalRows / 4, 256, 0, stream>>>(yb, W3, b3, outp);
}

// Round 6
// 2755.377 us; speedup vs baseline: 1.1109x; 1.1109x over previous
//
#include <hip/hip_runtime.h>
#include <hip/hip_bf16.h>

#define BB 256
#define TT 512
#define XS 40
#define HS 128
#define GS 512  // 4*HS

typedef __attribute__((ext_vector_type(8))) short bf16x8;
typedef __attribute__((ext_vector_type(4))) float f32x4;

__device__ __forceinline__ float fast_sigmoid(float x) {
    return __frcp_rn(1.0f + __expf(-x));
}
__device__ __forceinline__ float fast_tanh(float x) {
    x = fminf(fmaxf(x, -15.0f), 15.0f);
    float e = __expf(2.0f * x);
    return (e - 1.0f) * __frcp_rn(e + 1.0f);
}
__device__ __forceinline__ ushort f2bf(float f) {  // RNE float->bf16 bits
    uint u = __float_as_uint(f);
    u = u + 0x7FFFu + ((u >> 16) & 1u);
    return (ushort)(u >> 16);
}
__device__ __forceinline__ float bf2f(ushort h) {
    return __uint_as_float(((uint)h) << 16);
}

// ---- fragment-pack layout for M[R][K] (K padded to KC*32):
// elem (r,k) -> ((blkr*KC + kc)*64 + lane)*8 + e
//   blkr=r>>4, kc=k>>5, lane=(r&15)+16*((k>>3)&3), e=k&7
// A-frag / B-frag of mfma_f32_16x16x32_bf16 then loads as one dwordx4 at
// ((brg*KC+kc)*64 + l)*8  (verified mapping: round-3 passing kernel).

__global__ __launch_bounds__(256) void pack_k(
    const float* __restrict__ src, int R, int Kin, int stride, int coloff,
    int KC, ushort* __restrict__ dh, ushort* __restrict__ dl) {
    size_t p = (size_t)blockIdx.x * 256 + threadIdx.x;
    size_t total = (size_t)R * KC * 32;
    if (p >= total) return;
    int e = (int)(p & 7);
    int lane = (int)((p >> 3) & 63);
    size_t rest = p >> 9;
    int kc = (int)(rest % KC);
    int blkr = (int)(rest / KC);
    int r = blkr * 16 + (lane & 15);
    int k = kc * 32 + ((lane >> 4) & 3) * 8 + e;
    float v = (k < Kin) ? src[(size_t)r * stride + k + coloff] : 0.0f;
    ushort hb = f2bf(v);
    dh[p] = hb;
    dl[p] = f2bf(v - bf2f(hb));
}

// ---------------- MFMA GEMM: no LDS, frag-packed operands ----------------
// MODE 0 (proj): out fp32 [Lr*512+n] += bias1+bias2, A rows remapped via Tc chunk
// MODE 1 (head1): dual A source (x then y), relu, out packed bf16 z1 (K=128)
// MODE 2 (head2): out fp32 [Lr*128+n], relu
template <int KCA, int KCB, int MODE>
__global__ __launch_bounds__(256) void gemm_mf(
    const ushort* __restrict__ Ah, const ushort* __restrict__ Al,
    const ushort* __restrict__ Bh, const ushort* __restrict__ Bl,
    const ushort* __restrict__ A2h, const ushort* __restrict__ A2l,
    const ushort* __restrict__ B2h, const ushort* __restrict__ B2l,
    const float* __restrict__ bias1, const float* __restrict__ bias2,
    float* __restrict__ outf, ushort* __restrict__ outh, ushort* __restrict__ outl,
    int t0, int TcShift, int r0) {
    const int tid = threadIdx.x;
    const int w = tid >> 6, l = tid & 63;
    const int lr = l & 15, lk = l >> 4;
    const int Lr0 = blockIdx.x * 64 + w * 16;  // local out row-block base
    const int n0 = blockIdx.y * 64;

    int g0;
    if (MODE == 0) {
        int b = Lr0 >> TcShift;
        g0 = Lr0 + b * (TT - (1 << TcShift)) + t0;
    } else {
        g0 = r0 + Lr0;
    }
    const size_t brg = (size_t)(g0 >> 4);

    f32x4 acc[4] = {};

#pragma unroll
    for (int kc = 0; kc < KCA; ++kc) {
        bf16x8 ahi = *(const bf16x8*)(Ah + ((brg * KCA + kc) * 64 + l) * 8);
        bf16x8 alo = *(const bf16x8*)(Al + ((brg * KCA + kc) * 64 + l) * 8);
#pragma unroll
        for (int nt = 0; nt < 4; ++nt) {
            size_t nblk = (size_t)(blockIdx.y * 4 + nt);
            bf16x8 bhi = *(const bf16x8*)(Bh + ((nblk * KCA + kc) * 64 + l) * 8);
            bf16x8 blo = *(const bf16x8*)(Bl + ((nblk * KCA + kc) * 64 + l) * 8);
            acc[nt] = __builtin_amdgcn_mfma_f32_16x16x32_bf16(ahi, bhi, acc[nt], 0, 0, 0);
            acc[nt] = __builtin_amdgcn_mfma_f32_16x16x32_bf16(alo, bhi, acc[nt], 0, 0, 0);
            acc[nt] = __builtin_amdgcn_mfma_f32_16x16x32_bf16(ahi, blo, acc[nt], 0, 0, 0);
        }
    }
    if (KCB > 0) {
#pragma unroll
        for (int kc = 0; kc < (KCB > 0 ? KCB : 1); ++kc) {
            bf16x8 ahi = *(const bf16x8*)(A2h + ((brg * KCB + kc) * 64 + l) * 8);
            bf16x8 alo = *(const bf16x8*)(A2l + ((brg * KCB + kc) * 64 + l) * 8);
#pragma unroll
            for (int nt = 0; nt < 4; ++nt) {
                size_t nblk = (size_t)(blockIdx.y * 4 + nt);
                bf16x8 bhi = *(const bf16x8*)(B2h + ((nblk * KCB + kc) * 64 + l) * 8);
                bf16x8 blo = *(const bf16x8*)(B2l + ((nblk * KCB + kc) * 64 + l) * 8);
                acc[nt] = __builtin_amdgcn_mfma_f32_16x16x32_bf16(ahi, bhi, acc[nt], 0, 0, 0);
                acc[nt] = __builtin_amdgcn_mfma_f32_16x16x32_bf16(alo, bhi, acc[nt], 0, 0, 0);
                acc[nt] = __builtin_amdgcn_mfma_f32_16x16x32_bf16(ahi, blo, acc[nt], 0, 0, 0);
            }
        }
    }

    // epilogue: D[row=4*lk+e][col=lr] per n-tile (round-3-verified layout)
#pragma unroll
    for (int nt = 0; nt < 4; ++nt) {
        int n = n0 + nt * 16 + lr;
        float bsum = bias1[n] + ((MODE == 0) ? bias2[n] : 0.0f);
#pragma unroll
        for (int e = 0; e < 4; ++e) {
            int Lr = Lr0 + 4 * lk + e;
            float v = acc[nt][e] + bsum;
            if (MODE == 0) {
                outf[(size_t)Lr * GS + n] = v;
            } else if (MODE == 2) {
                outf[(size_t)Lr * HS + n] = fmaxf(v, 0.0f);
            } else {
                v = fmaxf(v, 0.0f);
                ushort hb = f2bf(v);
                ushort lb = f2bf(v - bf2f(hb));
                int blk = blockIdx.x * 4 + w;
                int kcz = n >> 5;
                int lane_p = (4 * lk + e) + 16 * ((n >> 3) & 3);
                size_t ad = ((size_t)(blk * 4 + kcz) * 64 + lane_p) * 8 + (n & 7);
                outh[ad] = hb;
                outl[ad] = lb;
            }
        }
    }
}

// ---------------- recurrence: 512 thr (thread=gate), 128 weights in AGPRs ----------------
#define REP32(M) M(0) M(1) M(2) M(3) M(4) M(5) M(6) M(7) M(8) M(9) M(10) M(11) \
    M(12) M(13) M(14) M(15) M(16) M(17) M(18) M(19) M(20) M(21) M(22) M(23) \
    M(24) M(25) M(26) M(27) M(28) M(29) M(30) M(31)

#define DECLW(q) float Aq##q##x, Aq##q##y, Aq##q##z, Aq##q##w;
#define LOADW(q) { float4 wv = wr[q]; \
    asm volatile("v_accvgpr_write_b32 %0, %1" : "=a"(Aq##q##x) : "v"(wv.x)); \
    asm volatile("v_accvgpr_write_b32 %0, %1" : "=a"(Aq##q##y) : "v"(wv.y)); \
    asm volatile("v_accvgpr_write_b32 %0, %1" : "=a"(Aq##q##z) : "v"(wv.z)); \
    asm volatile("v_accvgpr_write_b32 %0, %1" : "=a"(Aq##q##w) : "v"(wv.w)); }
#define DOTW(q) { float4 hv = h4[q]; float ta, tb, tc_, td; \
    asm volatile("v_accvgpr_read_b32 %0, %1" : "=v"(ta) : "a"(Aq##q##x)); \
    asm volatile("v_accvgpr_read_b32 %0, %1" : "=v"(tb) : "a"(Aq##q##y)); \
    asm volatile("v_accvgpr_read_b32 %0, %1" : "=v"(tc_) : "a"(Aq##q##z)); \
    asm volatile("v_accvgpr_read_b32 %0, %1" : "=v"(td) : "a"(Aq##q##w)); \
    s0 = fmaf(ta, hv.x, s0); s1 = fmaf(tb, hv.y, s1); \
    s2 = fmaf(tc_, hv.z, s2); s3 = fmaf(td, hv.w, s3); }

__global__ __launch_bounds__(512, 1) void lstm_rec6(
    const float* __restrict__ Whh, const float* __restrict__ xW,
    const float* __restrict__ h0, const float* __restrict__ c0,
    float* __restrict__ hstate, float* __restrict__ cstate,
    ushort* __restrict__ yh, ushort* __restrict__ yl, int Tc, int t0) {
    const int b = blockIdx.x;
    const int g = threadIdx.x;  // gate 0..511
    __shared__ __align__(16) float h_sh[HS];
    __shared__ float act[GS];

    const float4* wr = (const float4*)(Whh + (size_t)g * HS);
    REP32(DECLW)
    REP32(LOADW)

    float c = 0.0f;
    if (g < HS) {
        float hv;
        if (t0 == 0) {
            hv = h0[(size_t)b * HS + g];
            c = c0[(size_t)b * HS + g];
        } else {
            hv = hstate[(size_t)b * HS + g];
            c = cstate[(size_t)b * HS + g];
        }
        h_sh[g] = hv;
    }
    __syncthreads();

    const float* xWrow = xW + (size_t)b * Tc * GS;
    const float4* h4 = (const float4*)h_sh;
    const int gtype = g >> 7;  // 0=i 1=f 2=g 3=o (wave-uniform)
    const int u = g & 127;

    float a_cur = xWrow[g];

    for (int t = 0; t < Tc; ++t) {
        int tn = (t + 1 < Tc) ? t + 1 : t;
        float a_nxt = xWrow[(size_t)tn * GS + g];

        float s0 = 0.f, s1 = 0.f, s2 = 0.f, s3 = 0.f;
        REP32(DOTW)
        float v = (s0 + s1) + (s2 + s3) + a_cur;
        act[g] = (gtype == 2) ? fast_tanh(v) : fast_sigmoid(v);
        __syncthreads();
        if (g < HS) {
            float iv = act[u], fv = act[HS + u], gg = act[2 * HS + u], ov = act[3 * HS + u];
            c = fmaf(fv, c, iv * gg);
            float hv = ov * fast_tanh(c);
            h_sh[u] = hv;
            // packed bf16 hi/lo store of y (global flat row grow, k=u)
            int grow = b * TT + t0 + t;
            ushort hb = f2bf(hv);
            ushort lb = f2bf(hv - bf2f(hb));
            size_t ad = ((size_t)((grow >> 4) * 4 + (u >> 5)) * 64 +
                         ((grow & 15) + 16 * ((u >> 3) & 3))) * 8 + (u & 7);
            yh[ad] = hb;
            yl[ad] = lb;
            if (t == Tc - 1) {
                hstate[(size_t)b * HS + u] = hv;
                cstate[(size_t)b * HS + u] = c;
            }
        }
        __syncthreads();
        a_cur = a_nxt;
    }
}

// out[row] = dot(z2[row,:], W3[0,:]) + b3 — one wave per row
__global__ __launch_bounds__(256) void head_dot(
    const float* __restrict__ z2, const float* __restrict__ W3,
    const float* __restrict__ b3, float* __restrict__ out) {
    const int wave = threadIdx.x >> 6, lane = threadIdx.x & 63;
    const int row = blockIdx.x * 4 + wave;
    const float* zr = z2 + (size_t)row * HS;
    float v = zr[lane] * W3[lane] + zr[64 + lane] * W3[64 + lane];
#pragma unroll
    for (int m = 32; m >= 1; m >>= 1) v += __shfl_xor(v, m, 64);
    if (lane == 0) out[row] = v + b3[0];
}

extern "C" void kernel_launch(void* const* d_in, const int* in_sizes, int n_in,
                              void* d_out, int out_size, void* d_ws, size_t ws_size,
                              hipStream_t stream) {
    const float* x = (const float*)d_in[0];
    const float* h0 = (const float*)d_in[1];
    const float* c0 = (const float*)d_in[2];
    const float* Wih[3] = {(const float*)d_in[3], (const float*)d_in[7], (const float*)d_in[11]};
    const float* Whh[3] = {(const float*)d_in[4], (const float*)d_in[8], (const float*)d_in[12]};
    const float* bih[3] = {(const float*)d_in[5], (const float*)d_in[9], (const float*)d_in[13]};
    const float* bhh[3] = {(const float*)d_in[6], (const float*)d_in[10], (const float*)d_in[14]};
    const float* W1 = (const float*)d_in[15];
    const float* b1 = (const float*)d_in[16];
    const float* W2 = (const float*)d_in[17];
    const float* b2 = (const float*)d_in[18];
    const float* W3 = (const float*)d_in[19];
    const float* b3 = (const float*)d_in[20];
    float* outp = (float*)d_out;

    const size_t R = (size_t)BB * TT;  // 131072 flat rows

    // ---- workspace carve ----
    // fixed: x_pack(2), y_pack(2), weight packs, states; variable: xW (Tc)
    size_t fixed_b = R * 64 * 2 * 2          // x_pack hi+lo
                   + R * 128 * 2 * 2         // y_pack hi+lo
                   + (size_t)(512 * 64 + 2 * 512 * 128 + 128 * 64 + 2 * 128 * 128) * 2 * 2
                   + 2 * (size_t)BB * HS * 4 + 4096;
    int Tc = TT;
    while (Tc > 64) {
        size_t need = fixed_b + (size_t)BB * Tc * GS * 4;
        if (need <= ws_size) break;
        Tc >>= 1;
    }
    int TcShift = 31 - __builtin_clz(Tc);

    char* p = (char*)d_ws;
    float* xw = (float*)p;           p += (size_t)BB * Tc * GS * 4;
    ushort* xph = (ushort*)p;        p += R * 64 * 2;
    ushort* xpl = (ushort*)p;        p += R * 64 * 2;
    ushort* yph = (ushort*)p;        p += R * 128 * 2;
    ushort* ypl = (ushort*)p;        p += R * 128 * 2;
    ushort* w0h = (ushort*)p;        p += (size_t)512 * 64 * 2;
    ushort* w0l = (ushort*)p;        p += (size_t)512 * 64 * 2;
    ushort* w1h = (ushort*)p;        p += (size_t)512 * 128 * 2;
    ushort* w1l = (ushort*)p;        p += (size_t)512 * 128 * 2;
    ushort* w2h = (ushort*)p;        p += (size_t)512 * 128 * 2;
    ushort* w2l = (ushort*)p;        p += (size_t)512 * 128 * 2;
    ushort* w1xh = (ushort*)p;       p += (size_t)128 * 64 * 2;
    ushort* w1xl = (ushort*)p;       p += (size_t)128 * 64 * 2;
    ushort* w1yh = (ushort*)p;       p += (size_t)128 * 128 * 2;
    ushort* w1yl = (ushort*)p;       p += (size_t)128 * 128 * 2;
    ushort* w2mh = (ushort*)p;       p += (size_t)128 * 128 * 2;
    ushort* w2ml = (ushort*)p;       p += (size_t)128 * 128 * 2;
    float* hs = (float*)p;           p += (size_t)BB * HS * 4;
    float* cs = (float*)p;           p += (size_t)BB * HS * 4;

    // ---- pack inputs & weights ----
    auto packgrid = [](size_t total) { return dim3((unsigned)((total + 255) / 256)); };
    pack_k<<<packgrid(R * 64), 256, 0, stream>>>(x, (int)R, XS, XS, 0, 2, xph, xpl);
    pack_k<<<packgrid(512 * 64), 256, 0, stream>>>(Wih[0], 512, XS, XS, 0, 2, w0h, w0l);
    pack_k<<<packgrid(512 * 128), 256, 0, stream>>>(Wih[1], 512, HS, HS, 0, 4, w1h, w1l);
    pack_k<<<packgrid(512 * 128), 256, 0, stream>>>(Wih[2], 512, HS, HS, 0, 4, w2h, w2l);
    pack_k<<<packgrid(128 * 64), 256, 0, stream>>>(W1, 128, XS, XS + HS, 0, 2, w1xh, w1xl);
    pack_k<<<packgrid(128 * 128), 256, 0, stream>>>(W1, 128, HS, XS + HS, XS, 4, w1yh, w1yl);
    pack_k<<<packgrid(128 * 128), 256, 0, stream>>>(W2, 128, HS, HS, 0, 4, w2mh, w2ml);

    const ushort* wih_h[3] = {w0h, w1h, w2h};
    const ushort* wih_l[3] = {w0l, w1l, w2l};

    // ---- layers ----
    for (int l = 0; l < 3; ++l) {
        for (int t0 = 0; t0 < TT; t0 += Tc) {
            dim3 gp((unsigned)(BB * Tc / 64), 8);
            if (l == 0)
                gemm_mf<2, 0, 0><<<gp, 256, 0, stream>>>(
                    xph, xpl, wih_h[0], wih_l[0], nullptr, nullptr, nullptr, nullptr,
                    bih[0], bhh[0], xw, nullptr, nullptr, t0, TcShift, 0);
            else
                gemm_mf<4, 0, 0><<<gp, 256, 0, stream>>>(
                    yph, ypl, wih_h[l], wih_l[l], nullptr, nullptr, nullptr, nullptr,
                    bih[l], bhh[l], xw, nullptr, nullptr, t0, TcShift, 0);
            lstm_rec6<<<BB, 512, 0, stream>>>(
                Whh[l], xw, h0 + (size_t)l * BB * HS, c0 + (size_t)l * BB * HS,
                hs, cs, yph, ypl, Tc, t0);
        }
    }

    // ---- MLP head (chunked into xw region: z1 packs + z2) ----
    size_t xwbytes = (size_t)BB * Tc * GS * 4;
    size_t RcMax = (xwbytes / 1024) & ~(size_t)63;
    size_t Rc = (RcMax < R) ? RcMax : R;
    for (size_t r0 = 0; r0 < R; r0 += Rc) {
        size_t rows = ((R - r0) < Rc) ? (R - r0) : Rc;
        ushort* z1h = (ushort*)xw;
        ushort* z1l = z1h + rows * 128;
        float* z2 = (float*)(z1l + rows * 128);
        dim3 gh((unsigned)(rows / 64), 2);
        gemm_mf<2, 4, 1><<<gh, 256, 0, stream>>>(
            xph, xpl, w1xh, w1xl, yph, ypl, w1yh, w1yl,
            b1, nullptr, nullptr, z1h, z1l, 0, 0, (int)r0);
        gemm_mf<4, 0, 2><<<gh, 256, 0, stream>>>(
            z1h, z1l, w2mh, w2ml, nullptr, nullptr, nullptr, nullptr,
            b2, nullptr, z2, nullptr, nullptr, 0, 0, 0);
        head_dot<<<(unsigned)(rows / 4), 256, 0, stream>>>(z2, W3, b3, outp + r0);
    }
}